// Round 14
// baseline (490.231 us; speedup 1.0000x reference)
//
#include <hip/hip_runtime.h>
#include <hip/hip_bf16.h>
#include <math.h>

// Problem: S=128, B=16, D=H=512, O=256.
// Collapse 1: watch/sus are exactly s-independent -> [16,512] recurrence;
//             outs broadcasts [128,16,256].
// Collapse 2: recurrence is row-independent -> 16 independent b-recurrences.
// Collapse 3: post-recurrence work depends only on w_t -> fused under the
//   recurrence. 256 WGs, XCD-partitioned (round-robin wg%8 heuristic; pure
//   speed optimization, correctness mapping-independent):
//   wg&7 <  4 -> sync role (128 WGs = 16b x 8p on XCDs 0-3; parts of b
//                co-XCD at b&3; weight slices stay L2-warm).
//   wg&7 >= 4 -> worker for t (XCDs 4-7 absorb GEMM reads + outs writes).
// Worker LDS strides conflict-free: wtile 521 (9fr mod 32), Bh/Bl 42, osbuf 260.
// Workers sleep-poll pzw (tagged u32, memset-0 each call - REQUIRED);
// publishers never wait on workers; unique pzw slot per t.

#define S_LEN 128
#define B_SZ  16
#define H_SZ  512
#define O_SZ  256
#define ROWS  (S_LEN * B_SZ)   // 2048

#define OUTS_ELEMS  (S_LEN * S_LEN * B_SZ * O_SZ)   // 67,108,864
#define WATCH_ELEMS (S_LEN * B_SZ * H_SZ)           // 1,048,576

typedef float  f32x4  __attribute__((ext_vector_type(4)));
typedef __bf16 bf16x8 __attribute__((ext_vector_type(8)));

// ================= MFMA split-bf16 GEMM (prologue) ==========================
struct alignas(16) GemmLds {
  __bf16 Ah[64][40]; __bf16 Al[64][40];
  __bf16 Bh[64][40]; __bf16 Bl[64][40];
};

__device__ __forceinline__ void gemm_body(
    const float* __restrict__ A, const float* __restrict__ B,
    const float* __restrict__ bias0, const float* __restrict__ bias1,
    float* __restrict__ C, int N, int K, int bm, int bn, GemmLds& T)
{
  const int tid = threadIdx.x;
  const int w = tid >> 6, l = tid & 63;
  const int fr = l & 15, fg = l >> 4;
  f32x4 acc[4] = {{0,0,0,0},{0,0,0,0},{0,0,0,0},{0,0,0,0}};
  const int ar = tid >> 2, ak = (tid & 3) << 3;
  const int bk = tid >> 3, bc = (tid & 7) << 3;

  for (int k0 = 0; k0 < K; k0 += 32) {
    {
      const float* s = &A[(size_t)(bm + ar) * K + k0 + ak];
      const f32x4 v0 = *(const f32x4*)s, v1 = *(const f32x4*)(s + 4);
      const float vv[8] = {v0.x, v0.y, v0.z, v0.w, v1.x, v1.y, v1.z, v1.w};
      bf16x8 h, lo;
#pragma unroll
      for (int j = 0; j < 8; ++j) {
        const __bf16 hh = (__bf16)vv[j];
        h[j] = hh; lo[j] = (__bf16)(vv[j] - (float)hh);
      }
      *(bf16x8*)&T.Ah[ar][ak] = h;
      *(bf16x8*)&T.Al[ar][ak] = lo;
    }
    {
      const float* s = &B[(size_t)(k0 + bk) * N + bn + bc];
      const f32x4 v0 = *(const f32x4*)s, v1 = *(const f32x4*)(s + 4);
      const float vv[8] = {v0.x, v0.y, v0.z, v0.w, v1.x, v1.y, v1.z, v1.w};
#pragma unroll
      for (int j = 0; j < 8; ++j) {
        const __bf16 hh = (__bf16)vv[j];
        T.Bh[bc + j][bk] = hh;
        T.Bl[bc + j][bk] = (__bf16)(vv[j] - (float)hh);
      }
    }
    __syncthreads();
    const bf16x8 ah = *(const bf16x8*)&T.Ah[(w << 4) + fr][fg << 3];
    const bf16x8 al = *(const bf16x8*)&T.Al[(w << 4) + fr][fg << 3];
#pragma unroll
    for (int nr = 0; nr < 4; ++nr) {
      const bf16x8 bh = *(const bf16x8*)&T.Bh[(nr << 4) + fr][fg << 3];
      const bf16x8 bl = *(const bf16x8*)&T.Bl[(nr << 4) + fr][fg << 3];
      acc[nr] = __builtin_amdgcn_mfma_f32_16x16x32_bf16(ah, bh, acc[nr], 0, 0, 0);
      acc[nr] = __builtin_amdgcn_mfma_f32_16x16x32_bf16(al, bh, acc[nr], 0, 0, 0);
      acc[nr] = __builtin_amdgcn_mfma_f32_16x16x32_bf16(ah, bl, acc[nr], 0, 0, 0);
    }
    __syncthreads();
  }
#pragma unroll
  for (int nr = 0; nr < 4; ++nr) {
    const int gcol = bn + (nr << 4) + fr;
    float bb = bias0 ? bias0[gcol] : 0.f;
    if (bias1) bb += bias1[gcol];
#pragma unroll
    for (int r = 0; r < 4; ++r) {
      const int grow = bm + (w << 4) + (fg << 2) + r;
      C[(size_t)grow * N + gcol] = acc[nr][r] + bb;
    }
  }
}

__global__ __launch_bounds__(256) void gemm_mfma(
    const float* __restrict__ A, const float* __restrict__ B,
    const float* __restrict__ bias0, const float* __restrict__ bias1,
    float* __restrict__ C, int N, int K)
{
  __shared__ GemmLds T;
  gemm_body(A, B, bias0, bias1, C, N, K, blockIdx.y << 6, blockIdx.x << 6, T);
}

// ---------------- softmax over H then gate by x (in-place on logits) --------
__global__ __launch_bounds__(64) void softmax_gate(float* __restrict__ lg,
                                                   const float* __restrict__ x)
{
  const int r = blockIdx.x;
  const int lane = threadIdx.x;
  float v[8];
  float m = -1e30f;
#pragma unroll
  for (int i = 0; i < 8; ++i) {
    v[i] = lg[(r << 9) + (i << 6) + lane];
    m = fmaxf(m, v[i]);
  }
#pragma unroll
  for (int off = 32; off > 0; off >>= 1) m = fmaxf(m, __shfl_xor(m, off, 64));
  float s = 0.f;
#pragma unroll
  for (int i = 0; i < 8; ++i) { v[i] = expf(v[i] - m); s += v[i]; }
#pragma unroll
  for (int off = 32; off > 0; off >>= 1) s += __shfl_xor(s, off, 64);
  const float inv = 1.0f / s;
#pragma unroll
  for (int i = 0; i < 8; ++i) {
    const int idx = (r << 9) + (i << 6) + lane;
    lg[idx] = v[i] * inv * x[idx];
  }
}

// ================= fused recurrence + incremental downstream ================
// worker LDS: wtile f32[16][521] @0 (33344 B) | Bh bf16[256][42] @33344
// (21504) | Bl @54848 (21504) | osbuf f32[16][260] @76352 (16640) -> 92992 B
#define RAW_BYTES 92992
#define WT_S 521
#define BH_S 42
#define OS_S 260

__global__ __launch_bounds__(256, 1) void rec_fused(
    const float* __restrict__ cbuf,          // [128][16][512]
    const float* __restrict__ insw,          // [512][512]
    const float* __restrict__ outw,          // [512][256]
    const float* __restrict__ outb,          // [256]
    const float* __restrict__ susw,          // [512][512]
    const float* __restrict__ susb,          // [512]
    unsigned long long* __restrict__ pz,     // [16][16][512] u64 ring (sync)
    unsigned* __restrict__ pzw,              // [128][16][512] u32 tagged (MEMSET 0)
    float* __restrict__ w127g,               // [16][512] f32
    float* __restrict__ mbuf,                // [128][16][512]
    float* __restrict__ outp)                // outs base [128][128][16][256]
{
  __shared__ __align__(16) char raw[RAW_BYTES];
  const int wg  = blockIdx.x;
  const int tid = threadIdx.x;
  const int x8  = wg & 7;

  if (x8 < 4) {
    // ======== sync role on XCDs 0-3 (round-robin heuristic) ========
    float* wsm = (float*)raw;                      // [512]
    float (*red)[64] = (float (*)[64])(raw + 2048);
    int* okf = (int*)(raw + 3072);

    const int sidx = ((wg >> 3) << 2) | (wg & 3);  // 0..127
    const int b   = sidx & 15;                     // parts of b co-XCD (b&3)
    const int p   = sidx >> 4;
    const int cl  = tid & 63;
    const int kq  = tid >> 6;
    const int c   = (p << 6) + cl;
    const int kbase = kq << 7;

    f32x4 wr[32];
#pragma unroll
    for (int j = 0; j < 32; ++j) {
      wr[j].x = insw[((kbase + 4 * j + 0) << 9) + c];
      wr[j].y = insw[((kbase + 4 * j + 1) << 9) + c];
      wr[j].z = insw[((kbase + 4 * j + 2) << 9) + c];
      wr[j].w = insw[((kbase + 4 * j + 3) << 9) + c];
    }

    if (tid < 64) {
      const float v = tanhf(cbuf[(b << 9) + c]);
      const unsigned bits = __float_as_uint(v);
      const unsigned long long pk =
          (1ULL << 32) | (unsigned long long)bits;
      __hip_atomic_store(&pz[(b << 9) + c], pk, __ATOMIC_RELAXED,
                         __HIP_MEMORY_SCOPE_AGENT);
      __hip_atomic_store(&pzw[(b << 9) + c], (1u << 24) | (bits >> 8),
                         __ATOMIC_RELAXED, __HIP_MEMORY_SCOPE_AGENT);
    }

    for (int t = 1; t < S_LEN; ++t) {
      const float cv = cbuf[(t << 13) + (b << 9) + c];

      const unsigned long long* src =
          pz + (((t - 1) & 15) << 13) + (b << 9);
      unsigned long long v0, v1;
      for (;;) {
        v0 = __hip_atomic_load(&src[2 * tid], __ATOMIC_RELAXED,
                               __HIP_MEMORY_SCOPE_AGENT);
        v1 = __hip_atomic_load(&src[2 * tid + 1], __ATOMIC_RELAXED,
                               __HIP_MEMORY_SCOPE_AGENT);
        const bool ok = ((unsigned)(v0 >> 32) == (unsigned)t) &
                        ((unsigned)(v1 >> 32) == (unsigned)t);
        const unsigned long long m = __ballot(ok);
        if ((tid & 63) == 0) okf[tid >> 6] = (m + 1 == 0ULL);
        __syncthreads();
        const bool all = okf[0] && okf[1] && okf[2] && okf[3];
        __syncthreads();
        if (all) break;
      }
      wsm[2 * tid]     = __uint_as_float((unsigned)v0);
      wsm[2 * tid + 1] = __uint_as_float((unsigned)v1);
      __syncthreads();

      float a0 = 0.f, a1 = 0.f, a2 = 0.f, a3 = 0.f;
#pragma unroll
      for (int j = 0; j < 32; ++j) {
        const f32x4 wv = *(const f32x4*)&wsm[kbase + (j << 2)];
        a0 = fmaf(wr[j].x, wv.x, a0);
        a1 = fmaf(wr[j].y, wv.y, a1);
        a2 = fmaf(wr[j].z, wv.z, a2);
        a3 = fmaf(wr[j].w, wv.w, a3);
      }
      red[kq][cl] = (a0 + a1) + (a2 + a3);
      __syncthreads();
      if (tid < 64) {
        const float y = red[0][cl] + red[1][cl] + red[2][cl] + red[3][cl];
        const float v = tanhf(cv + y);
        const unsigned bits = __float_as_uint(v);
        const unsigned long long pk =
            ((unsigned long long)(unsigned)(t + 1) << 32) |
            (unsigned long long)bits;
        __hip_atomic_store(&pz[((t & 15) << 13) + (b << 9) + c], pk,
                           __ATOMIC_RELAXED, __HIP_MEMORY_SCOPE_AGENT);
        __hip_atomic_store(&pzw[(t << 13) + (b << 9) + c],
                           (((unsigned)(t + 1)) << 24) | (bits >> 8),
                           __ATOMIC_RELAXED, __HIP_MEMORY_SCOPE_AGENT);
        if (t == 127) w127g[(b << 9) + c] = v;
      }
    }
  } else {
    // ======== worker role on XCDs 4-7: t = 4*(wg>>3) + (x8-4) ========
    const int t  = ((wg >> 3) << 2) + (x8 - 4);    // 0..127
    const int l  = tid & 63, q = tid >> 6;
    const int fr = l & 15, fg = l >> 4;
    float*  wtile = (float*)raw;                   // [16][521]
    __bf16* Bh    = (__bf16*)(raw + 33344);        // [256][42]
    __bf16* Bl    = (__bf16*)(raw + 54848);        // [256][42]
    float*  osbuf = (float*)(raw + 76352);         // [16][260]

    // phase 1: acquire w_t (bf24-tagged) with sleep-backoff polling
    {
      const unsigned* src = pzw + (t << 13);
      const unsigned tg = (unsigned)(t + 1);
      for (int g = 0; g < 4; ++g) {
        unsigned v[8];
        int cnt = 0;
        for (;;) {
          bool ok = true;
#pragma unroll
          for (int i = 0; i < 8; ++i) {
            v[i] = __hip_atomic_load(&src[(g << 11) + (i << 8) + tid],
                                     __ATOMIC_RELAXED, __HIP_MEMORY_SCOPE_AGENT);
            ok &= ((v[i] >> 24) == tg);
          }
          if (__ballot(ok) == ~0ULL) break;
          if (cnt < 4)      __builtin_amdgcn_s_sleep(8);
          else if (cnt < 8) __builtin_amdgcn_s_sleep(32);
          else              __builtin_amdgcn_s_sleep(120);
          ++cnt;
        }
#pragma unroll
        for (int i = 0; i < 8; ++i) {
          const int idx = (g << 11) + (i << 8) + tid;
          wtile[(idx >> 9) * WT_S + (idx & 511)] = __uint_as_float(v[i] << 8);
        }
      }
      __syncthreads();
    }

    // phase 2a: os_t[16,256] = w_t @ out_w + out_b  (split-bf16 MFMA)
    {
      f32x4 acc[4] = {{0,0,0,0},{0,0,0,0},{0,0,0,0},{0,0,0,0}};
      for (int k0 = 0; k0 < 512; k0 += 32) {
#pragma unroll
        for (int kk = 0; kk < 32; ++kk) {
          const float v = outw[((k0 + kk) << 8) + tid];
          const __bf16 h = (__bf16)v;
          Bh[tid * BH_S + kk] = h;
          Bl[tid * BH_S + kk] = (__bf16)(v - (float)h);
        }
        __syncthreads();
        bf16x8 ah, al;
#pragma unroll
        for (int j = 0; j < 8; ++j) {
          const float v = wtile[fr * WT_S + k0 + (fg << 3) + j];
          const __bf16 h = (__bf16)v;
          ah[j] = h; al[j] = (__bf16)(v - (float)h);
        }
#pragma unroll
        for (int nr = 0; nr < 4; ++nr) {
          const int col = (q << 6) + (nr << 4) + fr;
          const bf16x8 bh = *(const bf16x8*)&Bh[col * BH_S + (fg << 3)];
          const bf16x8 bl = *(const bf16x8*)&Bl[col * BH_S + (fg << 3)];
          acc[nr] = __builtin_amdgcn_mfma_f32_16x16x32_bf16(ah, bh, acc[nr], 0, 0, 0);
          acc[nr] = __builtin_amdgcn_mfma_f32_16x16x32_bf16(al, bh, acc[nr], 0, 0, 0);
          acc[nr] = __builtin_amdgcn_mfma_f32_16x16x32_bf16(ah, bl, acc[nr], 0, 0, 0);
        }
        __syncthreads();
      }
#pragma unroll
      for (int nr = 0; nr < 4; ++nr) {
        const int col = (q << 6) + (nr << 4) + fr;
#pragma unroll
        for (int r = 0; r < 4; ++r)
          osbuf[((fg << 2) + r) * OS_S + col] = acc[nr][r] + outb[col];
      }
      __syncthreads();
    }

    // phase 3: stream outs[t][s][.][.] = os_t (2 MB nontemporal)
    {
      const int rb = tid >> 4, o0 = (tid & 15) << 4;
      const f32x4 d0 = *(const f32x4*)&osbuf[rb * OS_S + o0];
      const f32x4 d1 = *(const f32x4*)&osbuf[rb * OS_S + o0 + 4];
      const f32x4 d2 = *(const f32x4*)&osbuf[rb * OS_S + o0 + 8];
      const f32x4 d3 = *(const f32x4*)&osbuf[rb * OS_S + o0 + 12];
      f32x4* dst = (f32x4*)(outp + (size_t)t * 524288) + (tid << 2);
      for (int s = 0; s < S_LEN; ++s) {
        __builtin_nontemporal_store(d0, dst + 0);
        __builtin_nontemporal_store(d1, dst + 1);
        __builtin_nontemporal_store(d2, dst + 2);
        __builtin_nontemporal_store(d3, dst + 3);
        dst += 1024;
      }
    }

    // phase 2b: M_t[16,512] = w_t @ sus_w + sus_b (two 256-col halves)
    for (int half = 0; half < 2; ++half) {
      f32x4 am[4] = {{0,0,0,0},{0,0,0,0},{0,0,0,0},{0,0,0,0}};
      for (int k0 = 0; k0 < 512; k0 += 32) {
#pragma unroll
        for (int kk = 0; kk < 32; ++kk) {
          const float v = susw[((k0 + kk) << 9) + (half << 8) + tid];
          const __bf16 h = (__bf16)v;
          Bh[tid * BH_S + kk] = h;
          Bl[tid * BH_S + kk] = (__bf16)(v - (float)h);
        }
        __syncthreads();
        bf16x8 ah, al;
#pragma unroll
        for (int j = 0; j < 8; ++j) {
          const float v = wtile[fr * WT_S + k0 + (fg << 3) + j];
          const __bf16 h = (__bf16)v;
          ah[j] = h; al[j] = (__bf16)(v - (float)h);
        }
#pragma unroll
        for (int nr = 0; nr < 4; ++nr) {
          const int col = (q << 6) + (nr << 4) + fr;
          const bf16x8 bh = *(const bf16x8*)&Bh[col * BH_S + (fg << 3)];
          const bf16x8 bl = *(const bf16x8*)&Bl[col * BH_S + (fg << 3)];
          am[nr] = __builtin_amdgcn_mfma_f32_16x16x32_bf16(ah, bh, am[nr], 0, 0, 0);
          am[nr] = __builtin_amdgcn_mfma_f32_16x16x32_bf16(al, bh, am[nr], 0, 0, 0);
          am[nr] = __builtin_amdgcn_mfma_f32_16x16x32_bf16(ah, bl, am[nr], 0, 0, 0);
        }
        __syncthreads();
      }
#pragma unroll
      for (int nr = 0; nr < 4; ++nr) {
        const int col = (half << 8) + (q << 6) + (nr << 4) + fr;
#pragma unroll
        for (int r = 0; r < 4; ++r)
          mbuf[(t << 13) + (((fg << 2) + r) << 9) + col] = am[nr][r] + susb[col];
      }
    }
  }
}

// ---------------- sus scan (prefetch depth 4) -------------------------------
__global__ __launch_bounds__(256) void sus_scan(
    const float* __restrict__ M, float* __restrict__ s_small)
{
  const int gid = blockIdx.x * blockDim.x + threadIdx.x;  // 8192
  float s = 0.f;
  float n0 = M[gid];
  float n1 = M[(1 << 13) + gid];
  float n2 = M[(2 << 13) + gid];
  float n3 = M[(3 << 13) + gid];
  for (int t = 0; t < S_LEN - 4; ++t) {
    const float cur = n0;
    n0 = n1; n1 = n2; n2 = n3;
    n3 = M[((t + 4) << 13) + gid];
    s = tanhf(cur + s);
  }
  s = tanhf(n0 + s); s = tanhf(n1 + s); s = tanhf(n2 + s); s = tanhf(n3 + s);
  s_small[gid] = s;
}

// ---------------- watch/sus broadcast (8 MB) --------------------------------
__global__ __launch_bounds__(256) void bc_watch_sus(
    const f32x4* __restrict__ w127, const f32x4* __restrict__ s4,
    f32x4* __restrict__ watch_out, f32x4* __restrict__ sus_out)
{
  const int stride = gridDim.x * blockDim.x;
  for (int i = blockIdx.x * blockDim.x + threadIdx.x; i < (1 << 18); i += stride) {
    const int src = i & 2047;
    __builtin_nontemporal_store(w127[src], &watch_out[i]);
    __builtin_nontemporal_store(s4[src], &sus_out[i]);
  }
}

extern "C" void kernel_launch(void* const* d_in, const int* in_sizes, int n_in,
                              void* d_out, int out_size, void* d_ws, size_t ws_size,
                              hipStream_t stream)
{
  const float* x      = (const float*)d_in[0];
  const float* attn_w = (const float*)d_in[1];
  const float* attn_b = (const float*)d_in[2];
  const float* in_w   = (const float*)d_in[3];
  const float* in_b   = (const float*)d_in[4];
  const float* ins_w  = (const float*)d_in[5];
  const float* ins_b  = (const float*)d_in[6];
  const float* sus_w  = (const float*)d_in[7];
  const float* sus_b  = (const float*)d_in[8];
  const float* out_w  = (const float*)d_in[9];
  const float* out_b  = (const float*)d_in[10];

  // ws (bytes): cbuf [0,4M) | tmp [4,8M) (logits/R; pzw overlays after use)
  // | pz ring-16 [8,9M) | mbuf [9,13M) | w127g [13M,+32K) | s_small [+32K,+64K)
  float* ws    = (float*)d_ws;
  float* cbuf  = ws;
  float* tmp   = ws + (1 << 20);
  unsigned* pzw = (unsigned*)tmp;
  unsigned long long* pz = (unsigned long long*)(ws + (2 << 20));
  float* mbuf   = ws + (((size_t)9 << 20) >> 2);
  float* w127g  = ws + (((size_t)13 << 20) >> 2);
  float* s_small = w127g + 8192;

  float* outp   = (float*)d_out;
  float* watchp = outp + OUTS_ELEMS;
  float* susp   = watchp + WATCH_ELEMS;

  const dim3 blk(256);
  // logits = X @ attn_w + attn_b -> tmp   (MFMA split-bf16)
  gemm_mfma<<<dim3(8, 32), blk, 0, stream>>>(x, attn_w, attn_b, nullptr, tmp, 512, 512);
  // R = softmax(logits) * X   (in place on tmp)
  softmax_gate<<<dim3(2048), dim3(64), 0, stream>>>(tmp, x);
  // c = R @ in_w + in_b + ins_b -> cbuf   (tmp dead after this)
  gemm_mfma<<<dim3(8, 32), blk, 0, stream>>>(tmp, in_w, in_b, ins_b, cbuf, 512, 512);
  // REQUIRED: zero pzw (overlays tmp; tag byte 0 never matches t+1>=1).
  (void)hipMemsetAsync(pzw, 0, (size_t)4 << 20, stream);
  // fused recurrence + incremental os/M/outs (256 WGs, XCD-partitioned)
  rec_fused<<<dim3(256), blk, 0, stream>>>(cbuf, ins_w, out_w, out_b,
                                           sus_w, sus_b, pz, pzw, w127g,
                                           mbuf, outp);
  // elementwise sus scan -> s_small
  sus_scan<<<dim3(32), blk, 0, stream>>>(mbuf, s_small);
  // watch/sus broadcast (8 MB)
  bc_watch_sus<<<dim3(512), blk, 0, stream>>>(
      (const f32x4*)w127g, (const f32x4*)s_small,
      (f32x4*)watchp, (f32x4*)susp);
}

// Round 15
// 336.648 us; speedup vs baseline: 1.4562x; 1.4562x over previous
//
#include <hip/hip_runtime.h>
#include <hip/hip_bf16.h>
#include <math.h>

// Problem: S=128, B=16, D=H=512, O=256.
// Collapse 1: watch/sus are exactly s-independent -> [16,512] recurrence;
//             outs broadcasts [128,16,256].
// Collapse 2: recurrence is row-independent -> 16 independent b-recurrences.
// Pipeline = R10 (prologue MFMA GEMMs -> recurrence -> dual GEMM -> scan ->
// finalize). Fusion abandoned: R13/R14 proved worker fabric traffic inflates
// the sync chain more than the overlap saves.
// Recurrence change this round: wave-local poll. Wave kq's lanes poll exactly
// the 128 values its FMA consumes -> block consensus (okf + 2 syncthreads per
// poll iter) removed; wave-private wsm forwarding via lgkmcnt(0)+sched_barrier
// (rule #18); ONE syncthreads/step for the cross-wave red reduce, red parity-
// double-buffered to kill the WAR race across that barrier.
// Epoch-in-data u64 (epoch<<32|f32 bits): 0xAA poison never matches epoch t;
// values deterministic -> stale/cross-replay matches are bit-identical/safe.
// GEMMs: MFMA split-bf16 (hi/lo, 3 mfma_16x16x32 per pair, ~2^-16 rel err).

#define S_LEN 128
#define B_SZ  16
#define H_SZ  512
#define O_SZ  256
#define ROWS  (S_LEN * B_SZ)   // 2048

#define OUTS_ELEMS  (S_LEN * S_LEN * B_SZ * O_SZ)   // 67,108,864
#define WATCH_ELEMS (S_LEN * B_SZ * H_SZ)           // 1,048,576

typedef float  f32x4  __attribute__((ext_vector_type(4)));
typedef __bf16 bf16x8 __attribute__((ext_vector_type(8)));

// ================= MFMA split-bf16 GEMM =====================================
struct alignas(16) GemmLds {
  __bf16 Ah[64][40]; __bf16 Al[64][40];
  __bf16 Bh[64][40]; __bf16 Bl[64][40];
};

__device__ __forceinline__ void gemm_body(
    const float* __restrict__ A, const float* __restrict__ B,
    const float* __restrict__ bias0, const float* __restrict__ bias1,
    float* __restrict__ C, int N, int K, int bm, int bn, GemmLds& T)
{
  const int tid = threadIdx.x;
  const int w = tid >> 6, l = tid & 63;
  const int fr = l & 15, fg = l >> 4;
  f32x4 acc[4] = {{0,0,0,0},{0,0,0,0},{0,0,0,0},{0,0,0,0}};
  const int ar = tid >> 2, ak = (tid & 3) << 3;   // A staging: row, k8
  const int bk = tid >> 3, bc = (tid & 7) << 3;   // B staging: k, col8

  for (int k0 = 0; k0 < K; k0 += 32) {
    {
      const float* s = &A[(size_t)(bm + ar) * K + k0 + ak];
      const f32x4 v0 = *(const f32x4*)s, v1 = *(const f32x4*)(s + 4);
      const float vv[8] = {v0.x, v0.y, v0.z, v0.w, v1.x, v1.y, v1.z, v1.w};
      bf16x8 h, lo;
#pragma unroll
      for (int j = 0; j < 8; ++j) {
        const __bf16 hh = (__bf16)vv[j];
        h[j] = hh; lo[j] = (__bf16)(vv[j] - (float)hh);
      }
      *(bf16x8*)&T.Ah[ar][ak] = h;
      *(bf16x8*)&T.Al[ar][ak] = lo;
    }
    {
      const float* s = &B[(size_t)(k0 + bk) * N + bn + bc];
      const f32x4 v0 = *(const f32x4*)s, v1 = *(const f32x4*)(s + 4);
      const float vv[8] = {v0.x, v0.y, v0.z, v0.w, v1.x, v1.y, v1.z, v1.w};
#pragma unroll
      for (int j = 0; j < 8; ++j) {
        const __bf16 hh = (__bf16)vv[j];
        T.Bh[bc + j][bk] = hh;
        T.Bl[bc + j][bk] = (__bf16)(vv[j] - (float)hh);
      }
    }
    __syncthreads();
    const bf16x8 ah = *(const bf16x8*)&T.Ah[(w << 4) + fr][fg << 3];
    const bf16x8 al = *(const bf16x8*)&T.Al[(w << 4) + fr][fg << 3];
#pragma unroll
    for (int nr = 0; nr < 4; ++nr) {
      const bf16x8 bh = *(const bf16x8*)&T.Bh[(nr << 4) + fr][fg << 3];
      const bf16x8 bl = *(const bf16x8*)&T.Bl[(nr << 4) + fr][fg << 3];
      acc[nr] = __builtin_amdgcn_mfma_f32_16x16x32_bf16(ah, bh, acc[nr], 0, 0, 0);
      acc[nr] = __builtin_amdgcn_mfma_f32_16x16x32_bf16(al, bh, acc[nr], 0, 0, 0);
      acc[nr] = __builtin_amdgcn_mfma_f32_16x16x32_bf16(ah, bl, acc[nr], 0, 0, 0);
    }
    __syncthreads();
  }
#pragma unroll
  for (int nr = 0; nr < 4; ++nr) {
    const int gcol = bn + (nr << 4) + fr;
    float bb = bias0 ? bias0[gcol] : 0.f;
    if (bias1) bb += bias1[gcol];
#pragma unroll
    for (int r = 0; r < 4; ++r) {
      const int grow = bm + (w << 4) + (fg << 2) + r;
      C[(size_t)grow * N + gcol] = acc[nr][r] + bb;
    }
  }
}

__global__ __launch_bounds__(256) void gemm_mfma(
    const float* __restrict__ A, const float* __restrict__ B,
    const float* __restrict__ bias0, const float* __restrict__ bias1,
    float* __restrict__ C, int N, int K)
{
  __shared__ GemmLds T;
  gemm_body(A, B, bias0, bias1, C, N, K, blockIdx.y << 6, blockIdx.x << 6, T);
}

__global__ __launch_bounds__(256) void gemm_dual_mfma(
    const float* __restrict__ A,
    const float* __restrict__ B1, const float* __restrict__ b1, float* __restrict__ C1,
    const float* __restrict__ B2, const float* __restrict__ b2, float* __restrict__ C2)
{
  __shared__ GemmLds T;
  if (blockIdx.x < 8)
    gemm_body(A, B1, b1, nullptr, C1, 512, 512, blockIdx.y << 6, blockIdx.x << 6, T);
  else
    gemm_body(A, B2, b2, nullptr, C2, 256, 512, blockIdx.y << 6, (blockIdx.x - 8) << 6, T);
}

// ---------------- softmax over H then gate by x (in-place on logits) --------
__global__ __launch_bounds__(64) void softmax_gate(float* __restrict__ lg,
                                                   const float* __restrict__ x)
{
  const int r = blockIdx.x;      // 0..2047
  const int lane = threadIdx.x;  // 0..63
  float v[8];
  float m = -1e30f;
#pragma unroll
  for (int i = 0; i < 8; ++i) {
    v[i] = lg[(r << 9) + (i << 6) + lane];
    m = fmaxf(m, v[i]);
  }
#pragma unroll
  for (int off = 32; off > 0; off >>= 1) m = fmaxf(m, __shfl_xor(m, off, 64));
  float s = 0.f;
#pragma unroll
  for (int i = 0; i < 8; ++i) { v[i] = expf(v[i] - m); s += v[i]; }
#pragma unroll
  for (int off = 32; off > 0; off >>= 1) s += __shfl_xor(s, off, 64);
  const float inv = 1.0f / s;
#pragma unroll
  for (int i = 0; i < 8; ++i) {
    const int idx = (r << 9) + (i << 6) + lane;
    lg[idx] = v[i] * inv * x[idx];
  }
}

// ---------------- recurrence (R10 structure, wave-local poll) ----------------
// 128 WGs = 16 b x 8 parts; part owns cols [64p,64p+64); wave kq owns K-range
// [128kq,128kq+128). Thread tid polls pz[2tid,2tid+1] -> wave kq's 64 lanes
// poll exactly its FMA input range -> wave-local ballot exit, wave-private
// wsm (no barrier), ONE syncthreads/step for parity-dbuf red reduce.
__global__ __launch_bounds__(256, 1) void recurrence(
    const float* __restrict__ cbuf,          // [128][16][512]
    const float* __restrict__ insw,          // [512][512]
    float* __restrict__ wall,                // [128][16][512]
    unsigned long long* __restrict__ pz)     // [16][16][512] u64 ring
{
  __shared__ float wsm[H_SZ];        // wave-private slices (wave kq: [128kq,+128))
  __shared__ float red[2][4][64];    // parity-dbuf cross-wave reduce

  const int wg  = blockIdx.x;
  const int b   = wg & 15;
  const int p   = wg >> 4;           // 0..7
  const int tid = threadIdx.x;
  const int cl  = tid & 63;
  const int kq  = tid >> 6;          // wave 0..3
  const int c   = (p << 6) + cl;     // owned col
  const int kbase = kq << 7;

  // weights: wr[j][e] = ins_w[kbase+4j+e][c] (L2-restreamed; R4/R10-measured OK)
  f32x4 wr[32];
#pragma unroll
  for (int j = 0; j < 32; ++j) {
    wr[j].x = insw[((kbase + 4 * j + 0) << 9) + c];
    wr[j].y = insw[((kbase + 4 * j + 1) << 9) + c];
    wr[j].z = insw[((kbase + 4 * j + 2) << 9) + c];
    wr[j].w = insw[((kbase + 4 * j + 3) << 9) + c];
  }

  // t = 0: publish w0 = tanh(c0) with epoch 1 in slot 0
  if (tid < 64) {
    const float v = tanhf(cbuf[(b << 9) + c]);
    wall[(b << 9) + c] = v;
    const unsigned long long pk =
        (1ULL << 32) | (unsigned long long)__float_as_uint(v);
    __hip_atomic_store(&pz[(b << 9) + c], pk, __ATOMIC_RELAXED,
                       __HIP_MEMORY_SCOPE_AGENT);
  }

  for (int t = 1; t < S_LEN; ++t) {
    // prefetch c_t (independent of the chain)
    const float cv = cbuf[(t << 13) + (b << 9) + c];

    // wave-local poll: this wave's 64 lanes cover exactly [128kq,128kq+128)
    const unsigned long long* src =
        pz + (((t - 1) & 15) << 13) + (b << 9);
    unsigned long long v0, v1;
    for (;;) {
      v0 = __hip_atomic_load(&src[2 * tid], __ATOMIC_RELAXED,
                             __HIP_MEMORY_SCOPE_AGENT);
      v1 = __hip_atomic_load(&src[2 * tid + 1], __ATOMIC_RELAXED,
                             __HIP_MEMORY_SCOPE_AGENT);
      const bool ok = ((unsigned)(v0 >> 32) == (unsigned)t) &
                      ((unsigned)(v1 >> 32) == (unsigned)t);
      if (__ballot(ok) == ~0ULL) break;          // wave-local exit
    }
    // wave-private forwarding (only this wave reads this wsm range)
    wsm[2 * tid]     = __uint_as_float((unsigned)v0);
    wsm[2 * tid + 1] = __uint_as_float((unsigned)v1);
    asm volatile("s_waitcnt lgkmcnt(0)" ::: "memory");
    __builtin_amdgcn_sched_barrier(0);           // rule #18

    // partial dot over this wave's K range: 128 exact f32 FMAs
    float a0 = 0.f, a1 = 0.f, a2 = 0.f, a3 = 0.f;
#pragma unroll
    for (int j = 0; j < 32; ++j) {
      const f32x4 wv = *(const f32x4*)&wsm[kbase + (j << 2)];
      a0 = fmaf(wr[j].x, wv.x, a0);
      a1 = fmaf(wr[j].y, wv.y, a1);
      a2 = fmaf(wr[j].z, wv.z, a2);
      a3 = fmaf(wr[j].w, wv.w, a3);
    }
    red[t & 1][kq][cl] = (a0 + a1) + (a2 + a3);
    __syncthreads();                             // the ONE barrier per step
    if (tid < 64) {
      const float y = red[t & 1][0][cl] + red[t & 1][1][cl] +
                      red[t & 1][2][cl] + red[t & 1][3][cl];
      const float v = tanhf(cv + y);
      wall[(t << 13) + (b << 9) + c] = v;
      const unsigned long long pk =
          ((unsigned long long)(unsigned)(t + 1) << 32) |
          (unsigned long long)__float_as_uint(v);
      __hip_atomic_store(&pz[((t & 15) << 13) + (b << 9) + c], pk,
                         __ATOMIC_RELAXED, __HIP_MEMORY_SCOPE_AGENT);
    }
  }
}

// ---------------- sus scan (prefetch depth 4) -------------------------------
__global__ __launch_bounds__(256) void sus_scan(
    const float* __restrict__ M, float* __restrict__ s_small)
{
  const int gid = blockIdx.x * blockDim.x + threadIdx.x;  // 8192
  float s = 0.f;
  float n0 = M[gid];
  float n1 = M[(1 << 13) + gid];
  float n2 = M[(2 << 13) + gid];
  float n3 = M[(3 << 13) + gid];
  for (int t = 0; t < S_LEN - 4; ++t) {
    const float cur = n0;
    n0 = n1; n1 = n2; n2 = n3;
    n3 = M[((t + 4) << 13) + gid];
    s = tanhf(cur + s);
  }
  s = tanhf(n0 + s); s = tanhf(n1 + s); s = tanhf(n2 + s); s = tanhf(n3 + s);
  s_small[gid] = s;
}

// ---------------- finalize: outs + watch + sus broadcast --------------------
__global__ __launch_bounds__(256) void finalize(
    const f32x4* __restrict__ os4, f32x4* __restrict__ outs4,
    const f32x4* __restrict__ w127, const f32x4* __restrict__ s4,
    f32x4* __restrict__ watch_out, f32x4* __restrict__ sus_out)
{
  const int gid = blockIdx.x * blockDim.x + threadIdx.x;
  const int stride = gridDim.x * blockDim.x;
  for (int i = gid; i < (1 << 24); i += stride) {
    const int o4 = i & 63;
    const int b  = (i >> 6) & 15;
    const int t  = i >> 17;
    __builtin_nontemporal_store(os4[(((t << 4) + b) << 6) + o4], &outs4[i]);
  }
  if (gid < (1 << 18)) {
    const int src = gid & 2047;
    __builtin_nontemporal_store(w127[src], &watch_out[gid]);
    __builtin_nontemporal_store(s4[src], &sus_out[gid]);
  }
}

extern "C" void kernel_launch(void* const* d_in, const int* in_sizes, int n_in,
                              void* d_out, int out_size, void* d_ws, size_t ws_size,
                              hipStream_t stream)
{
  const float* x      = (const float*)d_in[0];
  const float* attn_w = (const float*)d_in[1];
  const float* attn_b = (const float*)d_in[2];
  const float* in_w   = (const float*)d_in[3];
  const float* in_b   = (const float*)d_in[4];
  const float* ins_w  = (const float*)d_in[5];
  const float* ins_b  = (const float*)d_in[6];
  const float* sus_w  = (const float*)d_in[7];
  const float* sus_b  = (const float*)d_in[8];
  const float* out_w  = (const float*)d_in[9];
  const float* out_b  = (const float*)d_in[10];

  // ws (bytes): cbuf [0,4M) | wall [4M,8M) | tmp->mbuf [8M,12M) | pz [12M,13M)
  // after recurrence, cbuf region reused: obuf [0,2M), s_small [2M,2M+32K)
  float* ws    = (float*)d_ws;
  float* cbuf  = ws;
  float* wallb = ws + (1 << 20);
  float* tmp   = ws + (2 << 20);
  float* mbuf  = tmp;
  unsigned long long* pz = (unsigned long long*)(ws + (3 << 20));
  float* obuf    = ws;
  float* s_small = ws + (1 << 19);

  float* outp   = (float*)d_out;
  float* watchp = outp + OUTS_ELEMS;
  float* susp   = watchp + WATCH_ELEMS;

  const dim3 blk(256);
  // logits = X @ attn_w + attn_b -> tmp   (MFMA split-bf16)
  gemm_mfma<<<dim3(8, 32), blk, 0, stream>>>(x, attn_w, attn_b, nullptr, tmp, 512, 512);
  // R = softmax(logits) * X   (in place on tmp)
  softmax_gate<<<dim3(2048), dim3(64), 0, stream>>>(tmp, x);
  // c = R @ in_w + in_b + ins_b -> cbuf
  gemm_mfma<<<dim3(8, 32), blk, 0, stream>>>(tmp, in_w, in_b, ins_b, cbuf, 512, 512);
  // sequential recurrence (no memset — epoch scheme replay-safe)
  recurrence<<<dim3(128), blk, 0, stream>>>(cbuf, ins_w, wallb, pz);
  // M = wall @ sus_w + sus_b -> mbuf ; out_small = wall @ out_w + out_b -> obuf
  gemm_dual_mfma<<<dim3(12, 32), blk, 0, stream>>>(wallb, sus_w, sus_b, mbuf,
                                                   out_w, out_b, obuf);
  // elementwise sus scan -> s_small
  sus_scan<<<dim3(32), blk, 0, stream>>>(mbuf, s_small);
  // outs broadcast (268 MB) + watch/sus broadcast (8 MB)
  finalize<<<dim3(4096), blk, 0, stream>>>(
      (const f32x4*)obuf, (f32x4*)d_out,
      (const f32x4*)(wallb + (127 << 13)), (const f32x4*)s_small,
      (f32x4*)watchp, (f32x4*)susp);
}